// Round 2
// baseline (647.482 us; speedup 1.0000x reference)
//
#include <hip/hip_runtime.h>

// SAGAN self-attention, B=4 C=256 H=W=64 (N=4096), CK=32.
//   f = fw@x+fb, g = gw@x+gb, hv = hw@x+hb         (channel 1x1 convs)
//   s[j,m] = sum_k f[k,j] g[k,m]
//   L[j]   = sum_m exp(s[j,m])        (softmax row sums; softmax rows indexed j)
//   sa[c,m]= sum_j (hv[c,j]/L[j]) * exp(s[j,m])    (bmm contracts attention ROW idx)
//   out    = gamma*sa + x
//
// ws layout (bytes) — total 10,747,904 (kept small: round-1 failure was ws
// overflow clobbering a neighboring allocation, visible only post-timing):
//   fgT  [4][4096][64]  bf16  @ 0         (2,097,152)  [n][o]: o<32=f^T, o>=32=g^T
//   hv/w [4][256][4096] bf16  @ 2097152   (8,388,608)  proj writes hv; wdiv -> w in place
//   Lp   [4][4][4096]   f32   @ 10485760  (262,144)    partial L sums (4 m-splits)

typedef __bf16 bf16x4 __attribute__((ext_vector_type(4)));
typedef __bf16 bf16x8 __attribute__((ext_vector_type(8)));
typedef float  f32x4  __attribute__((ext_vector_type(4)));

static __device__ __forceinline__ bf16x8 frag_cat(bf16x4 lo, bf16x4 hi) {
  bf16x8 r;
  r[0]=lo[0]; r[1]=lo[1]; r[2]=lo[2]; r[3]=lo[3];
  r[4]=hi[0]; r[5]=hi[1]; r[6]=hi[2]; r[7]=hi[3];
  return r;
}
// Fragment k-map: element e -> k = (lane>>4)*4 + (e&3) + 16*(e>>2).
// Used consistently for BOTH A and B operands of every MFMA -> correct by
// permutation-invariance of the contraction, independent of true HW layout.
static __device__ __forceinline__ bf16x8 load_frag(const __bf16* p) {
  return frag_cat(*(const bf16x4*)p, *(const bf16x4*)(p + 16));
}

// ---------------- proj: [320x256] @ [256x4096] per batch (fp32 in, bf16 staging) ----
__global__ __launch_bounds__(256) void k_proj(
    const float* __restrict__ fw, const float* __restrict__ gw,
    const float* __restrict__ hw, const float* __restrict__ x,
    const float* __restrict__ fb, const float* __restrict__ gb,
    const float* __restrict__ hb,
    __bf16* __restrict__ fgT, __bf16* __restrict__ hv) {
  __shared__ __bf16 As[32][36];   // W tile  [m][k], +4 pad
  __shared__ __bf16 Bs[32][36];   // x tile transposed [n][k], +4 pad
  const int b = blockIdx.z, m0 = blockIdx.y * 32, n0 = blockIdx.x * 32;
  const int t = threadIdx.x;
  const int w = t >> 6, lane = t & 63, r16 = lane & 15, h = lane >> 4;
  const int msub = w >> 1, nsub = w & 1;
  const float* xb = x + (size_t)b * (256 * 4096);
  f32x4 acc = {};
  const int srow = t >> 3, s4 = (t & 7) * 4;
  const int wrow = m0 + srow;
  const float* wsrc = wrow < 32 ? (fw + wrow * 256)
                    : wrow < 64 ? (gw + (wrow - 32) * 256)
                                : (hw + (wrow - 64) * 256);
  for (int k0 = 0; k0 < 256; k0 += 32) {
    f32x4 wv = *(const f32x4*)(wsrc + k0 + s4);
    bf16x4 wo; wo[0]=(__bf16)wv[0]; wo[1]=(__bf16)wv[1];
    wo[2]=(__bf16)wv[2]; wo[3]=(__bf16)wv[3];
    *(bf16x4*)&As[srow][s4] = wo;
    f32x4 xv = *(const f32x4*)&xb[(size_t)(k0 + srow) * 4096 + n0 + s4];
    Bs[s4 + 0][srow] = (__bf16)xv[0]; Bs[s4 + 1][srow] = (__bf16)xv[1];
    Bs[s4 + 2][srow] = (__bf16)xv[2]; Bs[s4 + 3][srow] = (__bf16)xv[3];
    __syncthreads();
    const __bf16* ap = &As[msub * 16 + r16][h * 4];
    const __bf16* bp = &Bs[nsub * 16 + r16][h * 4];
    bf16x8 a  = frag_cat(*(const bf16x4*)ap, *(const bf16x4*)(ap + 16));
    bf16x8 bb = frag_cat(*(const bf16x4*)bp, *(const bf16x4*)(bp + 16));
    acc = __builtin_amdgcn_mfma_f32_16x16x32_bf16(a, bb, acc, 0, 0, 0);
    __syncthreads();
  }
  const int nn = n0 + nsub * 16 + r16;
  #pragma unroll
  for (int r = 0; r < 4; ++r) {
    const int row = m0 + msub * 16 + h * 4 + r;   // verified C/D: row=(lane>>4)*4+reg
    const float bias = row < 32 ? fb[row] : (row < 64 ? gb[row - 32] : hb[row - 64]);
    const float val = acc[r] + bias;
    if (row < 64) fgT[((size_t)b * 4096 + nn) * 64 + row] = (__bf16)val;
    else          hv[((size_t)b * 256 + (row - 64)) * 4096 + nn] = (__bf16)val;
  }
}

// ---------------- pass1: L[i] = sum_m exp(f_i . g_m)  (partial over m-quarter) ----
__global__ __launch_bounds__(256) void k_pass1(const __bf16* __restrict__ fgT,
                                               float* __restrict__ Lp) {
  const int b = blockIdx.z, ms = blockIdx.y;
  const int w = threadIdx.x >> 6, lane = threadIdx.x & 63, r16 = lane & 15, h = lane >> 4;
  const int ibase = blockIdx.x * 64 + w * 16;
  const __bf16* fg = fgT + (size_t)b * (4096 * 64);
  const bf16x8 afrag = load_frag(fg + (size_t)(ibase + r16) * 64 + h * 4);   // f rows i
  const f32x4 zero = {};
  float ls0 = 0.f, ls1 = 0.f, ls2 = 0.f, ls3 = 0.f;
  for (int mt = 0; mt < 64; ++mt) {
    const int mb = ms * 1024 + mt * 16;
    bf16x8 gfrag = load_frag(fg + (size_t)(mb + r16) * 64 + 32 + h * 4);     // g cols m
    f32x4 d = __builtin_amdgcn_mfma_f32_16x16x32_bf16(afrag, gfrag, zero, 0, 0, 0);
    ls0 += __expf(d[0]); ls1 += __expf(d[1]); ls2 += __expf(d[2]); ls3 += __expf(d[3]);
  }
  #pragma unroll
  for (int off = 1; off < 16; off <<= 1) {
    ls0 += __shfl_xor(ls0, off); ls1 += __shfl_xor(ls1, off);
    ls2 += __shfl_xor(ls2, off); ls3 += __shfl_xor(ls3, off);
  }
  if (r16 == 0) {
    f32x4 o = {ls0, ls1, ls2, ls3};                 // rows i = ibase + h*4 + r
    *(f32x4*)&Lp[(size_t)(b * 4 + ms) * 4096 + ibase + h * 4] = o;
  }
}

// ---------------- wdiv: w = bf16(hv / L), in place ----------------
__global__ __launch_bounds__(256) void k_wdiv(__bf16* __restrict__ hv,
                                              const float* __restrict__ Lp) {
  const int stride = gridDim.x * blockDim.x;
  for (int i = blockIdx.x * blockDim.x + threadIdx.x; i < 1048576; i += stride) {
    const int e = i * 4;
    const int b = e >> 20;          // hv layout [b][256][4096], 2^20 elems per batch
    const int j = e & 4095;         // spatial index
    bf16x4 h4 = *(const bf16x4*)(hv + e);
    const float* lp = Lp + (size_t)b * (4 * 4096) + j;
    f32x4 L = *(const f32x4*)lp;
    L += *(const f32x4*)(lp + 4096);
    L += *(const f32x4*)(lp + 8192);
    L += *(const f32x4*)(lp + 12288);
    bf16x4 o;
    o[0] = (__bf16)((float)h4[0] / L[0]); o[1] = (__bf16)((float)h4[1] / L[1]);
    o[2] = (__bf16)((float)h4[2] / L[2]); o[3] = (__bf16)((float)h4[3] / L[3]);
    *(bf16x4*)(hv + e) = o;
  }
}

// ---------------- pass2: sa[c,m] = sum_j w[c,j] exp(s[j,m]); out = gamma*sa + x ----
// 8 waves: wave = (chalf<<2)|msub. Block covers 64 m-cols x 256 c-rows.
// MFMA1 D (rows j, cols m) after exp is IN-REGISTER exactly the B-fragment of
// MFMA2 under the shared k-map  k = (lane>>4)*4 + (e&3) + 16*(e>>2).
__global__ __launch_bounds__(512) void k_pass2(const __bf16* __restrict__ fgT,
    const __bf16* __restrict__ wbf, const float* __restrict__ x,
    const float* __restrict__ gamma, float* __restrict__ out) {
  const int b = blockIdx.y, mblk = blockIdx.x;
  const int t = threadIdx.x, w = t >> 6, lane = t & 63, r16 = lane & 15, h = lane >> 4;
  const int msub = w & 3, chalf = w >> 2;
  const int mbase = mblk * 64 + msub * 16;
  const __bf16* fg = fgT + (size_t)b * (4096 * 64);
  const bf16x8 gfrag = load_frag(fg + (size_t)(mbase + r16) * 64 + 32 + h * 4); // g cols m (invariant)
  const __bf16* wb = wbf + ((size_t)b * 256 + chalf * 128) * 4096;
  f32x4 acc[8] = {};
  const f32x4 zero = {};
  for (int jt = 0; jt < 128; ++jt) {
    const int jbase = jt * 32;
    bf16x8 efrag;
    #pragma unroll
    for (int js = 0; js < 2; ++js) {
      bf16x8 ffrag = load_frag(fg + (size_t)(jbase + js * 16 + r16) * 64 + h * 4); // f rows j
      f32x4 d = __builtin_amdgcn_mfma_f32_16x16x32_bf16(ffrag, gfrag, zero, 0, 0, 0);
      #pragma unroll
      for (int r = 0; r < 4; ++r) efrag[js * 4 + r] = (__bf16)__expf(d[r]);
    }
    #pragma unroll
    for (int ct = 0; ct < 8; ++ct) {
      bf16x8 afrag = load_frag(wb + (size_t)(ct * 16 + r16) * 4096 + jbase + h * 4);
      acc[ct] = __builtin_amdgcn_mfma_f32_16x16x32_bf16(afrag, efrag, acc[ct], 0, 0, 0);
    }
  }
  const float gm = gamma[0];
  const float* xb = x + (size_t)b * (256 * 4096);
  float* ob = out + (size_t)b * (256 * 4096);
  #pragma unroll
  for (int ct = 0; ct < 8; ++ct) {
    #pragma unroll
    for (int r = 0; r < 4; ++r) {
      const int c = chalf * 128 + ct * 16 + h * 4 + r;
      const size_t idx = (size_t)c * 4096 + (mbase + r16);
      ob[idx] = gm * acc[ct][r] + xb[idx];
    }
  }
}

extern "C" void kernel_launch(void* const* d_in, const int* in_sizes, int n_in,
                              void* d_out, int out_size, void* d_ws, size_t ws_size,
                              hipStream_t stream) {
  const float* x     = (const float*)d_in[0];
  const float* fw    = (const float*)d_in[1];
  const float* fb    = (const float*)d_in[2];
  const float* gw    = (const float*)d_in[3];
  const float* gb    = (const float*)d_in[4];
  const float* hw    = (const float*)d_in[5];
  const float* hb    = (const float*)d_in[6];
  const float* gamma = (const float*)d_in[7];
  float* out = (float*)d_out;

  char* wsb = (char*)d_ws;
  __bf16* fgT = (__bf16*)(wsb);
  __bf16* hv  = (__bf16*)(wsb + 2097152);
  float*  Lp  = (float*) (wsb + 10485760);

  k_proj<<<dim3(128, 10, 4), dim3(256), 0, stream>>>(fw, gw, hw, x, fb, gb, hb, fgT, hv);
  k_pass1<<<dim3(64, 4, 4), dim3(256), 0, stream>>>(fgT, Lp);
  k_wdiv<<<dim3(1024), dim3(256), 0, stream>>>(hv, Lp);
  k_pass2<<<dim3(64, 4), dim3(512), 0, stream>>>(fgT, hv, x, gamma, out);
}

// Round 3
// 197.131 us; speedup vs baseline: 3.2845x; 3.2845x over previous
//
#include <hip/hip_runtime.h>

// SAGAN self-attention, B=4 C=256 H=W=64 (N=4096), CK=32.
//   f = fw@x+fb, g = gw@x+gb, hv = hw@x+hb         (channel 1x1 convs)
//   s[j,m] = sum_k f[k,j] g[k,m]
//   L[j]   = sum_m exp(s[j,m])        (softmax row sums; softmax rows indexed j)
//   sa[c,m]= sum_j (hv[c,j]/L[j]) * exp(s[j,m])    (bmm contracts attention ROW idx)
//   out    = gamma*sa + x
//
// ws layout (bytes) — total 10,747,904:
//   fgT  [4][4096][64]  bf16  @ 0         (2,097,152)  [n][o]: o<32=f^T, o>=32=g^T
//   hv/w [4][256][4096] bf16  @ 2097152   (8,388,608)  proj writes hv; wdiv -> w in place
//   Lp   [4][4][4096]   f32   @ 10485760  (262,144)    partial L sums (4 m-splits)

typedef __bf16 bf16x4 __attribute__((ext_vector_type(4)));
typedef __bf16 bf16x8 __attribute__((ext_vector_type(8)));
typedef float  f32x4  __attribute__((ext_vector_type(4)));

static __device__ __forceinline__ bf16x8 frag_cat(bf16x4 lo, bf16x4 hi) {
  bf16x8 r;
  r[0]=lo[0]; r[1]=lo[1]; r[2]=lo[2]; r[3]=lo[3];
  r[4]=hi[0]; r[5]=hi[1]; r[6]=hi[2]; r[7]=hi[3];
  return r;
}
// kappa k-map (MANDATORY wherever the k-axis is tied to an MFMA D output):
//   element e -> k = (lane>>4)*4 + (e&3) + 16*(e>>2)
// Free axes (channel contraction in proj/MFMA1/pass1) use the contiguous map
//   element e -> k = (lane>>4)*8 + e      (single 16B load)
// Both are valid as long as A and B of the same MFMA share the map.

// ---------------- proj: [320x256] @ [256x4096] per batch (fp32 in, bf16 staging) ----
__global__ __launch_bounds__(256) void k_proj(
    const float* __restrict__ fw, const float* __restrict__ gw,
    const float* __restrict__ hw, const float* __restrict__ x,
    const float* __restrict__ fb, const float* __restrict__ gb,
    const float* __restrict__ hb,
    __bf16* __restrict__ fgT, __bf16* __restrict__ hv) {
  __shared__ __bf16 As[32][36];   // W tile  [m][k], +4 pad
  __shared__ __bf16 Bs[32][36];   // x tile transposed [n][k], +4 pad
  const int b = blockIdx.z, m0 = blockIdx.y * 32, n0 = blockIdx.x * 32;
  const int t = threadIdx.x;
  const int w = t >> 6, lane = t & 63, r16 = lane & 15, h = lane >> 4;
  const int msub = w >> 1, nsub = w & 1;
  const float* xb = x + (size_t)b * (256 * 4096);
  f32x4 acc = {};
  const int srow = t >> 3, s4 = (t & 7) * 4;
  const int wrow = m0 + srow;
  const float* wsrc = wrow < 32 ? (fw + wrow * 256)
                    : wrow < 64 ? (gw + (wrow - 32) * 256)
                                : (hw + (wrow - 64) * 256);
  for (int k0 = 0; k0 < 256; k0 += 32) {
    f32x4 wv = *(const f32x4*)(wsrc + k0 + s4);
    bf16x4 wo; wo[0]=(__bf16)wv[0]; wo[1]=(__bf16)wv[1];
    wo[2]=(__bf16)wv[2]; wo[3]=(__bf16)wv[3];
    *(bf16x4*)&As[srow][s4] = wo;
    f32x4 xv = *(const f32x4*)&xb[(size_t)(k0 + srow) * 4096 + n0 + s4];
    Bs[s4 + 0][srow] = (__bf16)xv[0]; Bs[s4 + 1][srow] = (__bf16)xv[1];
    Bs[s4 + 2][srow] = (__bf16)xv[2]; Bs[s4 + 3][srow] = (__bf16)xv[3];
    __syncthreads();
    const __bf16* ap = &As[msub * 16 + r16][h * 4];
    const __bf16* bp = &Bs[nsub * 16 + r16][h * 4];
    bf16x8 a  = frag_cat(*(const bf16x4*)ap, *(const bf16x4*)(ap + 16));
    bf16x8 bb = frag_cat(*(const bf16x4*)bp, *(const bf16x4*)(bp + 16));
    acc = __builtin_amdgcn_mfma_f32_16x16x32_bf16(a, bb, acc, 0, 0, 0);
    __syncthreads();
  }
  const int nn = n0 + nsub * 16 + r16;
  #pragma unroll
  for (int r = 0; r < 4; ++r) {
    const int row = m0 + msub * 16 + h * 4 + r;   // verified C/D: row=(lane>>4)*4+reg
    const float bias = row < 32 ? fb[row] : (row < 64 ? gb[row - 32] : hb[row - 64]);
    const float val = acc[r] + bias;
    if (row < 64) fgT[((size_t)b * 4096 + nn) * 64 + row] = (__bf16)val;
    else          hv[((size_t)b * 256 + (row - 64)) * 4096 + nn] = (__bf16)val;
  }
}

// ---------------- pass1: L[i] = sum_m exp(f_i . g_m)  (partial over m-quarter) ----
__global__ __launch_bounds__(256) void k_pass1(const __bf16* __restrict__ fgT,
                                               float* __restrict__ Lp) {
  const int b = blockIdx.z, ms = blockIdx.y;
  const int w = threadIdx.x >> 6, lane = threadIdx.x & 63, r16 = lane & 15, h = lane >> 4;
  const int ibase = blockIdx.x * 64 + w * 16;
  const __bf16* fg = fgT + (size_t)b * (4096 * 64);
  // contiguous channel map (8h+e) for BOTH operands -> single 16B loads
  const bf16x8 afrag = *(const bf16x8*)(fg + (size_t)(ibase + r16) * 64 + h * 8);
  const f32x4 zero = {};
  float ls0 = 0.f, ls1 = 0.f, ls2 = 0.f, ls3 = 0.f;
  for (int mt = 0; mt < 64; mt += 2) {
    const int mb = ms * 1024 + mt * 16;
    bf16x8 g0 = *(const bf16x8*)(fg + (size_t)(mb + r16) * 64 + 32 + h * 8);
    bf16x8 g1 = *(const bf16x8*)(fg + (size_t)(mb + 16 + r16) * 64 + 32 + h * 8);
    f32x4 d0 = __builtin_amdgcn_mfma_f32_16x16x32_bf16(afrag, g0, zero, 0, 0, 0);
    f32x4 d1 = __builtin_amdgcn_mfma_f32_16x16x32_bf16(afrag, g1, zero, 0, 0, 0);
    ls0 += __expf(d0[0]) + __expf(d1[0]); ls1 += __expf(d0[1]) + __expf(d1[1]);
    ls2 += __expf(d0[2]) + __expf(d1[2]); ls3 += __expf(d0[3]) + __expf(d1[3]);
  }
  #pragma unroll
  for (int off = 1; off < 16; off <<= 1) {
    ls0 += __shfl_xor(ls0, off); ls1 += __shfl_xor(ls1, off);
    ls2 += __shfl_xor(ls2, off); ls3 += __shfl_xor(ls3, off);
  }
  if (r16 == 0) {
    f32x4 o = {ls0, ls1, ls2, ls3};                 // rows i = ibase + h*4 + r
    *(f32x4*)&Lp[(size_t)(b * 4 + ms) * 4096 + ibase + h * 4] = o;
  }
}

// ---------------- wdiv: w = bf16(hv / L), in place ----------------
__global__ __launch_bounds__(256) void k_wdiv(__bf16* __restrict__ hv,
                                              const float* __restrict__ Lp) {
  const int stride = gridDim.x * blockDim.x;
  for (int i = blockIdx.x * blockDim.x + threadIdx.x; i < 1048576; i += stride) {
    const int e = i * 4;
    const int b = e >> 20;          // hv layout [b][256][4096], 2^20 elems per batch
    const int j = e & 4095;         // spatial index
    bf16x4 h4 = *(const bf16x4*)(hv + e);
    const float* lp = Lp + (size_t)b * (4 * 4096) + j;
    f32x4 L = *(const f32x4*)lp;
    L += *(const f32x4*)(lp + 4096);
    L += *(const f32x4*)(lp + 8192);
    L += *(const f32x4*)(lp + 12288);
    bf16x4 o;
    o[0] = (__bf16)((float)h4[0] / L[0]); o[1] = (__bf16)((float)h4[1] / L[1]);
    o[2] = (__bf16)((float)h4[2] / L[2]); o[3] = (__bf16)((float)h4[3] / L[3]);
    *(bf16x4*)(hv + e) = o;
  }
}

// ---------------- pass2: sa[c,m] = sum_j w[c,j] exp(s[j,m]); out = gamma*sa + x ----
// 8 waves: wave = (chalf<<2)|msub. Block covers 64 m-cols x 256 c-rows.
// w tile [256 c][32 j] LDS-staged (double-buffered, row stride 36 elems = 72B,
// verified conflict-free for the kappa ds_read_b64 pattern). ffrag prefetched
// one jt ahead; stage loads issued before compute, written after (T14).
// MFMA1 D (rows j, cols m) after exp is IN-REGISTER exactly the B-fragment of
// MFMA2 under the kappa map k = (lane>>4)*4 + (e&3) + 16*(e>>2).
__global__ __launch_bounds__(512, 1) void k_pass2(const __bf16* __restrict__ fgT,
    const __bf16* __restrict__ wbf, const float* __restrict__ x,
    const float* __restrict__ gamma, float* __restrict__ out) {
  __shared__ __bf16 wS[2][256][36];   // 36,864 B
  const int b = blockIdx.y, mblk = blockIdx.x;
  const int t = threadIdx.x, w = t >> 6, lane = t & 63, r16 = lane & 15, h = lane >> 4;
  const int msub = w & 3, chalf = w >> 2;
  const int mbase = mblk * 64 + msub * 16;
  const __bf16* fg = fgT + (size_t)b * (4096 * 64);
  const __bf16* wb = wbf + (size_t)b * 256 * 4096;
  // gfrag: MFMA1 B operand, contiguous channel map (invariant over jt)
  const bf16x8 gfrag = *(const bf16x8*)(fg + (size_t)(mbase + r16) * 64 + 32 + h * 8);
  // staging: thread t handles 32B of row srow (16 elems at shalf*16)
  const int srow = t >> 1, shalf = t & 1;
  const __bf16* sbase = wb + (size_t)srow * 4096 + shalf * 16;
  __bf16* sdst0 = &wS[0][srow][shalf * 16];
  __bf16* sdst1 = &wS[1][srow][shalf * 16];

  f32x4 acc[8] = {};
  const f32x4 zero = {};

  // prologue: stage tile 0, load ffrag for jt=0
  {
    uint4 a = *(const uint4*)(sbase);
    uint4 c = *(const uint4*)(sbase + 8);
    uint2* d = (uint2*)sdst0;
    d[0] = *((const uint2*)&a + 0); d[1] = *((const uint2*)&a + 1);
    d[2] = *((const uint2*)&c + 0); d[3] = *((const uint2*)&c + 1);
  }
  bf16x8 f0 = *(const bf16x8*)(fg + (size_t)(r16) * 64 + h * 8);
  bf16x8 f1 = *(const bf16x8*)(fg + (size_t)(16 + r16) * 64 + h * 8);
  __syncthreads();

  for (int jt = 0; jt < 128; ++jt) {
    const int cur = jt & 1;
    const int jb2 = (jt + 1) * 32;
    uint4 pa, pc; bf16x8 nf0, nf1;
    if (jt < 127) {   // issue next-tile global loads early (latency hides under compute)
      pa  = *(const uint4*)(sbase + jb2);
      pc  = *(const uint4*)(sbase + jb2 + 8);
      nf0 = *(const bf16x8*)(fg + (size_t)(jb2 + r16) * 64 + h * 8);
      nf1 = *(const bf16x8*)(fg + (size_t)(jb2 + 16 + r16) * 64 + h * 8);
    }
    // E tile: MFMA1 (contiguous channel map) + exp -> efrag (kappa layout on j)
    f32x4 d0 = __builtin_amdgcn_mfma_f32_16x16x32_bf16(f0, gfrag, zero, 0, 0, 0);
    f32x4 d1 = __builtin_amdgcn_mfma_f32_16x16x32_bf16(f1, gfrag, zero, 0, 0, 0);
    bf16x8 efrag;
    #pragma unroll
    for (int r = 0; r < 4; ++r) {
      efrag[r]     = (__bf16)__expf(d0[r]);
      efrag[4 + r] = (__bf16)__expf(d1[r]);
    }
    // MFMA2 x8 with w from LDS (kappa map on j: bytes h*8 and h*8+32 of the row)
    #pragma unroll
    for (int ct = 0; ct < 8; ++ct) {
      const __bf16* ap = &wS[cur][chalf * 128 + ct * 16 + r16][h * 4];
      bf16x8 afrag = frag_cat(*(const bf16x4*)ap, *(const bf16x4*)(ap + 16));
      acc[ct] = __builtin_amdgcn_mfma_f32_16x16x32_bf16(afrag, efrag, acc[ct], 0, 0, 0);
    }
    if (jt < 127) {   // write next tile (other buffer: no hazard with this iter's reads)
      uint2* d = (uint2*)((jt & 1) ? sdst0 : sdst1);
      d[0] = *((const uint2*)&pa + 0); d[1] = *((const uint2*)&pa + 1);
      d[2] = *((const uint2*)&pc + 0); d[3] = *((const uint2*)&pc + 1);
      f0 = nf0; f1 = nf1;
    }
    __syncthreads();
  }

  const float gm = gamma[0];
  const float* xb = x + (size_t)b * (256 * 4096);
  float* ob = out + (size_t)b * (256 * 4096);
  #pragma unroll
  for (int ct = 0; ct < 8; ++ct) {
    #pragma unroll
    for (int r = 0; r < 4; ++r) {
      const int c = chalf * 128 + ct * 16 + h * 4 + r;
      const size_t idx = (size_t)c * 4096 + (mbase + r16);
      ob[idx] = gm * acc[ct][r] + xb[idx];
    }
  }
}

extern "C" void kernel_launch(void* const* d_in, const int* in_sizes, int n_in,
                              void* d_out, int out_size, void* d_ws, size_t ws_size,
                              hipStream_t stream) {
  const float* x     = (const float*)d_in[0];
  const float* fw    = (const float*)d_in[1];
  const float* fb    = (const float*)d_in[2];
  const float* gw    = (const float*)d_in[3];
  const float* gb    = (const float*)d_in[4];
  const float* hw    = (const float*)d_in[5];
  const float* hb    = (const float*)d_in[6];
  const float* gamma = (const float*)d_in[7];
  float* out = (float*)d_out;

  char* wsb = (char*)d_ws;
  __bf16* fgT = (__bf16*)(wsb);
  __bf16* hv  = (__bf16*)(wsb + 2097152);
  float*  Lp  = (float*) (wsb + 10485760);

  k_proj<<<dim3(128, 10, 4), dim3(256), 0, stream>>>(fw, gw, hw, x, fb, gb, hb, fgT, hv);
  k_pass1<<<dim3(64, 4, 4), dim3(256), 0, stream>>>(fgT, Lp);
  k_wdiv<<<dim3(1024), dim3(256), 0, stream>>>(hv, Lp);
  k_pass2<<<dim3(64, 4), dim3(512), 0, stream>>>(fgT, hv, x, gamma, out);
}

// Round 4
// 167.319 us; speedup vs baseline: 3.8697x; 1.1782x over previous
//
#include <hip/hip_runtime.h>

// SAGAN self-attention, B=4 C=256 H=W=64 (N=4096), CK=32.
//   f = fw@x+fb, g = gw@x+gb, hv = hw@x+hb         (channel 1x1 convs)
//   s[j,m] = sum_k f[k,j] g[k,m]
//   L[j]   = sum_m exp(s[j,m])        (softmax row sums; softmax rows indexed j)
//   sa[c,m]= sum_j (hv[c,j]/L[j]) * exp(s[j,m])    (bmm contracts attention ROW idx)
//   out    = gamma*sa + x
//
// ws layout (bytes) — total 10,747,904:
//   fgT  [4][4096][64]  bf16  @ 0         (2,097,152)  [n][o]: o<32=f^T, o>=32=g^T
//   hv/w [4][256][4096] bf16  @ 2097152   (8,388,608)  proj writes hv; wdiv -> w in place
//   Lp   [4][4][4096]   f32   @ 10485760  (262,144)    partial L sums (4 m-splits)

typedef __bf16 bf16x4 __attribute__((ext_vector_type(4)));
typedef __bf16 bf16x8 __attribute__((ext_vector_type(8)));
typedef float  f32x4  __attribute__((ext_vector_type(4)));

static __device__ __forceinline__ bf16x8 frag_cat(bf16x4 lo, bf16x4 hi) {
  bf16x8 r;
  r[0]=lo[0]; r[1]=lo[1]; r[2]=lo[2]; r[3]=lo[3];
  r[4]=hi[0]; r[5]=hi[1]; r[6]=hi[2]; r[7]=hi[3];
  return r;
}
// kappa k-map (MANDATORY wherever the k-axis is tied to an MFMA D output):
//   element e -> k = (lane>>4)*4 + (e&3) + 16*(e>>2)
// Free axes (channel contraction in proj/MFMA1/pass1) use the contiguous map
//   element e -> k = (lane>>4)*8 + e      (single 16B load)
// Both are valid as long as A and B of the same MFMA share the map.

// ---------------- proj: [320x256] @ [256x4096] per batch (fp32 in, bf16 staging) ----
__global__ __launch_bounds__(256) void k_proj(
    const float* __restrict__ fw, const float* __restrict__ gw,
    const float* __restrict__ hw, const float* __restrict__ x,
    const float* __restrict__ fb, const float* __restrict__ gb,
    const float* __restrict__ hb,
    __bf16* __restrict__ fgT, __bf16* __restrict__ hv) {
  __shared__ __bf16 As[32][36];   // W tile  [m][k], +4 pad
  __shared__ __bf16 Bs[32][36];   // x tile transposed [n][k], +4 pad
  const int b = blockIdx.z, m0 = blockIdx.y * 32, n0 = blockIdx.x * 32;
  const int t = threadIdx.x;
  const int w = t >> 6, lane = t & 63, r16 = lane & 15, h = lane >> 4;
  const int msub = w >> 1, nsub = w & 1;
  const float* xb = x + (size_t)b * (256 * 4096);
  f32x4 acc = {};
  const int srow = t >> 3, s4 = (t & 7) * 4;
  const int wrow = m0 + srow;
  const float* wsrc = wrow < 32 ? (fw + wrow * 256)
                    : wrow < 64 ? (gw + (wrow - 32) * 256)
                                : (hw + (wrow - 64) * 256);
  for (int k0 = 0; k0 < 256; k0 += 32) {
    f32x4 wv = *(const f32x4*)(wsrc + k0 + s4);
    bf16x4 wo; wo[0]=(__bf16)wv[0]; wo[1]=(__bf16)wv[1];
    wo[2]=(__bf16)wv[2]; wo[3]=(__bf16)wv[3];
    *(bf16x4*)&As[srow][s4] = wo;
    f32x4 xv = *(const f32x4*)&xb[(size_t)(k0 + srow) * 4096 + n0 + s4];
    Bs[s4 + 0][srow] = (__bf16)xv[0]; Bs[s4 + 1][srow] = (__bf16)xv[1];
    Bs[s4 + 2][srow] = (__bf16)xv[2]; Bs[s4 + 3][srow] = (__bf16)xv[3];
    __syncthreads();
    const __bf16* ap = &As[msub * 16 + r16][h * 4];
    const __bf16* bp = &Bs[nsub * 16 + r16][h * 4];
    bf16x8 a  = frag_cat(*(const bf16x4*)ap, *(const bf16x4*)(ap + 16));
    bf16x8 bb = frag_cat(*(const bf16x4*)bp, *(const bf16x4*)(bp + 16));
    acc = __builtin_amdgcn_mfma_f32_16x16x32_bf16(a, bb, acc, 0, 0, 0);
    __syncthreads();
  }
  const int nn = n0 + nsub * 16 + r16;
  #pragma unroll
  for (int r = 0; r < 4; ++r) {
    const int row = m0 + msub * 16 + h * 4 + r;   // verified C/D: row=(lane>>4)*4+reg
    const float bias = row < 32 ? fb[row] : (row < 64 ? gb[row - 32] : hb[row - 64]);
    const float val = acc[r] + bias;
    if (row < 64) fgT[((size_t)b * 4096 + nn) * 64 + row] = (__bf16)val;
    else          hv[((size_t)b * 256 + (row - 64)) * 4096 + nn] = (__bf16)val;
  }
}

// ---------------- pass1: L[i] = sum_m exp(f_i . g_m)  (partial over m-quarter) ----
__global__ __launch_bounds__(256) void k_pass1(const __bf16* __restrict__ fgT,
                                               float* __restrict__ Lp) {
  const int b = blockIdx.z, ms = blockIdx.y;
  const int w = threadIdx.x >> 6, lane = threadIdx.x & 63, r16 = lane & 15, h = lane >> 4;
  const int ibase = blockIdx.x * 64 + w * 16;
  const __bf16* fg = fgT + (size_t)b * (4096 * 64);
  // contiguous channel map (8h+e) for BOTH operands -> single 16B loads
  const bf16x8 afrag = *(const bf16x8*)(fg + (size_t)(ibase + r16) * 64 + h * 8);
  const f32x4 zero = {};
  float ls0 = 0.f, ls1 = 0.f, ls2 = 0.f, ls3 = 0.f;
  for (int mt = 0; mt < 64; mt += 2) {
    const int mb = ms * 1024 + mt * 16;
    bf16x8 g0 = *(const bf16x8*)(fg + (size_t)(mb + r16) * 64 + 32 + h * 8);
    bf16x8 g1 = *(const bf16x8*)(fg + (size_t)(mb + 16 + r16) * 64 + 32 + h * 8);
    f32x4 d0 = __builtin_amdgcn_mfma_f32_16x16x32_bf16(afrag, g0, zero, 0, 0, 0);
    f32x4 d1 = __builtin_amdgcn_mfma_f32_16x16x32_bf16(afrag, g1, zero, 0, 0, 0);
    ls0 += __expf(d0[0]) + __expf(d1[0]); ls1 += __expf(d0[1]) + __expf(d1[1]);
    ls2 += __expf(d0[2]) + __expf(d1[2]); ls3 += __expf(d0[3]) + __expf(d1[3]);
  }
  #pragma unroll
  for (int off = 1; off < 16; off <<= 1) {
    ls0 += __shfl_xor(ls0, off); ls1 += __shfl_xor(ls1, off);
    ls2 += __shfl_xor(ls2, off); ls3 += __shfl_xor(ls3, off);
  }
  if (r16 == 0) {
    f32x4 o = {ls0, ls1, ls2, ls3};                 // rows i = ibase + h*4 + r
    *(f32x4*)&Lp[(size_t)(b * 4 + ms) * 4096 + ibase + h * 4] = o;
  }
}

// ---------------- wdiv: w = bf16(hv / L), in place ----------------
__global__ __launch_bounds__(256) void k_wdiv(__bf16* __restrict__ hv,
                                              const float* __restrict__ Lp) {
  const int stride = gridDim.x * blockDim.x;
  for (int i = blockIdx.x * blockDim.x + threadIdx.x; i < 1048576; i += stride) {
    const int e = i * 4;
    const int b = e >> 20;          // hv layout [b][256][4096], 2^20 elems per batch
    const int j = e & 4095;         // spatial index
    bf16x4 h4 = *(const bf16x4*)(hv + e);
    const float* lp = Lp + (size_t)b * (4 * 4096) + j;
    f32x4 L = *(const f32x4*)lp;
    L += *(const f32x4*)(lp + 4096);
    L += *(const f32x4*)(lp + 8192);
    L += *(const f32x4*)(lp + 12288);
    bf16x4 o;
    o[0] = (__bf16)((float)h4[0] / L[0]); o[1] = (__bf16)((float)h4[1] / L[1]);
    o[2] = (__bf16)((float)h4[2] / L[2]); o[3] = (__bf16)((float)h4[3] / L[3]);
    *(bf16x4*)(hv + e) = o;
  }
}

// ---------------- pass2: sa[c,m] = sum_j w[c,j] exp(s[j,m]); out = gamma*sa + x ----
// 8 waves: wave = (chalf<<2)|msub. Block covers 64 m-cols x 256 c-rows.
// J-tile = 64 (2 kappa sub-tiles), double-buffered XOR-swizzled LDS [256][64]
// (byte ^= (row&7)<<4 within the 128B row -> ds_read 4-way max, writes 16B).
// XCD-aware bid remap: batch b pinned to 2 XCDs so its 2MB w stays L2-resident.
// MFMA1 D (rows j, cols m) after exp is IN-REGISTER exactly the B-fragment of
// MFMA2 under the kappa map k = (lane>>4)*4 + (e&3) + 16*(e>>2).
__global__ __launch_bounds__(512, 1) void k_pass2(const __bf16* __restrict__ fgT,
    const __bf16* __restrict__ wbf, const float* __restrict__ x,
    const float* __restrict__ gamma, float* __restrict__ out) {
  __shared__ __bf16 wS[2][256][64];   // 65,536 B
  const int bid = blockIdx.x;                       // 0..255, XCD = bid&7 (round-robin)
  const int b = (bid & 7) >> 1;                     // 2 XCDs per batch
  const int mblk = ((bid >> 3) << 1) | (bid & 1);   // 0..63
  const int t = threadIdx.x, w = t >> 6, lane = t & 63, r16 = lane & 15, h = lane >> 4;
  const int msub = w & 3, chalf = w >> 2;
  const int mbase = mblk * 64 + msub * 16;
  const __bf16* fg = fgT + (size_t)b * (4096 * 64);
  const __bf16* wb = wbf + (size_t)b * 256 * 4096;
  // gfrag: MFMA1 B operand, contiguous channel map (invariant over j)
  const bf16x8 gfrag = *(const bf16x8*)(fg + (size_t)(mbase + r16) * 64 + 32 + h * 8);
  // staging: thread t covers row (t>>1), 32 elems at col (t&1)*32, as 4x16B
  const int srow = t >> 1, scol = (t & 1) * 32;
  const __bf16* sgsrc = wb + (size_t)srow * 4096 + scol;
  const int swrz = (srow & 7) << 4;                 // write-side XOR
  char* srow0 = (char*)&wS[0][srow][0];
  char* srow1 = (char*)&wS[1][srow][0];
  const int rswz = (r16 & 7) << 4;                  // read-side XOR (row&7 == r16&7)

  f32x4 acc[8] = {};
  const f32x4 zero = {};

  // prologue: stage tile 0, load f fragments for tile 0
  #pragma unroll
  for (int c = 0; c < 4; ++c) {
    uint4 v = *(const uint4*)(sgsrc + c * 8);
    *(uint4*)(srow0 + (((scol * 2 + c * 16) ^ swrz))) = v;
  }
  bf16x8 fq0 = *(const bf16x8*)(fg + (size_t)(r16) * 64 + h * 8);
  bf16x8 fq1 = *(const bf16x8*)(fg + (size_t)(16 + r16) * 64 + h * 8);
  bf16x8 fq2 = *(const bf16x8*)(fg + (size_t)(32 + r16) * 64 + h * 8);
  bf16x8 fq3 = *(const bf16x8*)(fg + (size_t)(48 + r16) * 64 + h * 8);
  __syncthreads();

  for (int it = 0; it < 64; ++it) {
    const int cur = it & 1;
    const int jbn = (it + 1) * 64;
    uint4 pw0, pw1, pw2, pw3; bf16x8 nf0, nf1, nf2, nf3;
    if (it < 63) {   // issue next-tile global loads early (hide under compute)
      pw0 = *(const uint4*)(sgsrc + jbn);
      pw1 = *(const uint4*)(sgsrc + jbn + 8);
      pw2 = *(const uint4*)(sgsrc + jbn + 16);
      pw3 = *(const uint4*)(sgsrc + jbn + 24);
      nf0 = *(const bf16x8*)(fg + (size_t)(jbn + r16) * 64 + h * 8);
      nf1 = *(const bf16x8*)(fg + (size_t)(jbn + 16 + r16) * 64 + h * 8);
      nf2 = *(const bf16x8*)(fg + (size_t)(jbn + 32 + r16) * 64 + h * 8);
      nf3 = *(const bf16x8*)(fg + (size_t)(jbn + 48 + r16) * 64 + h * 8);
    }
    // E tiles: MFMA1 + exp -> efrag0 (j 0..31), efrag1 (j 32..63), kappa on j
    f32x4 d0 = __builtin_amdgcn_mfma_f32_16x16x32_bf16(fq0, gfrag, zero, 0, 0, 0);
    f32x4 d1 = __builtin_amdgcn_mfma_f32_16x16x32_bf16(fq1, gfrag, zero, 0, 0, 0);
    f32x4 d2 = __builtin_amdgcn_mfma_f32_16x16x32_bf16(fq2, gfrag, zero, 0, 0, 0);
    f32x4 d3 = __builtin_amdgcn_mfma_f32_16x16x32_bf16(fq3, gfrag, zero, 0, 0, 0);
    bf16x8 ef0, ef1;
    #pragma unroll
    for (int r = 0; r < 4; ++r) {
      ef0[r]     = (__bf16)__expf(d0[r]);
      ef0[4 + r] = (__bf16)__expf(d1[r]);
      ef1[r]     = (__bf16)__expf(d2[r]);
      ef1[4 + r] = (__bf16)__expf(d3[r]);
    }
    // MFMA2 x16 with w from swizzled LDS (kappa map on j)
    #pragma unroll
    for (int ct = 0; ct < 8; ++ct) {
      const char* rp = (const char*)&wS[cur][chalf * 128 + ct * 16 + r16][0];
      bf16x8 a0 = frag_cat(*(const bf16x4*)(rp + ((h * 8) ^ rswz)),
                           *(const bf16x4*)(rp + ((h * 8 + 32) ^ rswz)));
      acc[ct] = __builtin_amdgcn_mfma_f32_16x16x32_bf16(a0, ef0, acc[ct], 0, 0, 0);
      bf16x8 a1 = frag_cat(*(const bf16x4*)(rp + ((64 + h * 8) ^ rswz)),
                           *(const bf16x4*)(rp + ((64 + h * 8 + 32) ^ rswz)));
      acc[ct] = __builtin_amdgcn_mfma_f32_16x16x32_bf16(a1, ef1, acc[ct], 0, 0, 0);
    }
    if (it < 63) {   // write next tile into the other buffer
      char* sd = cur ? srow0 : srow1;
      *(uint4*)(sd + ((scol * 2 +  0) ^ swrz)) = pw0;
      *(uint4*)(sd + ((scol * 2 + 16) ^ swrz)) = pw1;
      *(uint4*)(sd + ((scol * 2 + 32) ^ swrz)) = pw2;
      *(uint4*)(sd + ((scol * 2 + 48) ^ swrz)) = pw3;
      fq0 = nf0; fq1 = nf1; fq2 = nf2; fq3 = nf3;
    }
    __syncthreads();
  }

  const float gm = gamma[0];
  const float* xb = x + (size_t)b * (256 * 4096);
  float* ob = out + (size_t)b * (256 * 4096);
  #pragma unroll
  for (int ct = 0; ct < 8; ++ct) {
    #pragma unroll
    for (int r = 0; r < 4; ++r) {
      const int c = chalf * 128 + ct * 16 + h * 4 + r;
      const size_t idx = (size_t)c * 4096 + (mbase + r16);
      ob[idx] = gm * acc[ct][r] + xb[idx];
    }
  }
}

extern "C" void kernel_launch(void* const* d_in, const int* in_sizes, int n_in,
                              void* d_out, int out_size, void* d_ws, size_t ws_size,
                              hipStream_t stream) {
  const float* x     = (const float*)d_in[0];
  const float* fw    = (const float*)d_in[1];
  const float* fb    = (const float*)d_in[2];
  const float* gw    = (const float*)d_in[3];
  const float* gb    = (const float*)d_in[4];
  const float* hw    = (const float*)d_in[5];
  const float* hb    = (const float*)d_in[6];
  const float* gamma = (const float*)d_in[7];
  float* out = (float*)d_out;

  char* wsb = (char*)d_ws;
  __bf16* fgT = (__bf16*)(wsb);
  __bf16* hv  = (__bf16*)(wsb + 2097152);
  float*  Lp  = (float*) (wsb + 10485760);

  k_proj<<<dim3(128, 10, 4), dim3(256), 0, stream>>>(fw, gw, hw, x, fb, gb, hb, fgT, hv);
  k_pass1<<<dim3(64, 4, 4), dim3(256), 0, stream>>>(fgT, Lp);
  k_wdiv<<<dim3(1024), dim3(256), 0, stream>>>(hv, Lp);
  k_pass2<<<dim3(256), dim3(512), 0, stream>>>(fgT, hv, x, gamma, out);
}

// Round 5
// 162.869 us; speedup vs baseline: 3.9755x; 1.0273x over previous
//
#include <hip/hip_runtime.h>

// SAGAN self-attention, B=4 C=256 H=W=64 (N=4096), CK=32.
//   f = fw@x+fb, g = gw@x+gb, hv = hw@x+hb         (channel 1x1 convs)
//   s[j,m] = sum_k f[k,j] g[k,m]
//   L[j]   = sum_m exp(s[j,m])
//   sa[c,m]= sum_j (hv[c,j]/L[j]) * exp(s[j,m])
//   out    = gamma*sa + x
//
// ws layout (bytes) — total 10,747,904:
//   fgT  [4][4096][64]  bf16  @ 0         (2,097,152)  [n][o]: o<32=f^T, o>=32=g^T
//   hv/w [4][256][4096] bf16  @ 2097152   (8,388,608)  proj writes hv; wdiv -> w in place
//   Lp   [4][4][4096]   f32   @ 10485760  (262,144)    partial L sums (4 m-splits)
//
// All grids use the bijective XCD map (grid%8==0): b = (bid&7)>>1 pins each
// batch's fgT (0.5MB) + w (2MB) to one XCD pair's 8MB L2 for the whole chain.

typedef __bf16 bf16x4 __attribute__((ext_vector_type(4)));
typedef __bf16 bf16x8 __attribute__((ext_vector_type(8)));
typedef float  f32x4  __attribute__((ext_vector_type(4)));

static __device__ __forceinline__ bf16x8 frag_cat(bf16x4 lo, bf16x4 hi) {
  bf16x8 r;
  r[0]=lo[0]; r[1]=lo[1]; r[2]=lo[2]; r[3]=lo[3];
  r[4]=hi[0]; r[5]=hi[1]; r[6]=hi[2]; r[7]=hi[3];
  return r;
}
static __device__ __forceinline__ bf16x8 cvt8(f32x4 lo, f32x4 hi) {
  bf16x8 r;
  r[0]=(__bf16)lo[0]; r[1]=(__bf16)lo[1]; r[2]=(__bf16)lo[2]; r[3]=(__bf16)lo[3];
  r[4]=(__bf16)hi[0]; r[5]=(__bf16)hi[1]; r[6]=(__bf16)hi[2]; r[7]=(__bf16)hi[3];
  return r;
}
// kappa k-map (MANDATORY wherever the k-axis is tied to an MFMA D output):
//   element e -> k = (lane>>4)*4 + (e&3) + 16*(e>>2)
// Free axes (channel contraction) use the contiguous map e -> k=(lane>>4)*8+e
// (single 16B load). Valid as long as A and B of one MFMA share the map.

// ---------------- proj: x read ONCE; block = 64 n-cols x all 320 m-rows ----------
// 8 waves = (mq 0..3 [80 m-rows], nsub 0..1 [32 n]). K-loop 8 steps of 32,
// x tile (fp32->bf16) double-buffered in LDS [64 n][40 k] (stride 40: 16B-aligned
// rows, 8 bank phases). W fragments read fp32 from L2 + in-register cvt.
__global__ __launch_bounds__(512, 1) void k_proj(
    const float* __restrict__ fw, const float* __restrict__ gw,
    const float* __restrict__ hw, const float* __restrict__ x,
    const float* __restrict__ fb, const float* __restrict__ gb,
    const float* __restrict__ hb,
    __bf16* __restrict__ fgT, __bf16* __restrict__ hv) {
  __shared__ __bf16 Bs[2][64][40];   // 10,240 B
  const int bid = blockIdx.x;
  const int b = (bid & 7) >> 1;
  const int n0 = (((bid >> 3) << 1) | (bid & 1)) * 64;
  const int t = threadIdx.x, w = t >> 6, lane = t & 63, r16 = lane & 15, h = lane >> 4;
  const int nsub = w & 1, mq = w >> 1;
  const float* xb = x + (size_t)b * (256 * 4096);
  // per-mt W row pointer (each 16-row tile never straddles f/g/h boundaries)
  const float* Wp[5];
  #pragma unroll
  for (int mt = 0; mt < 5; ++mt) {
    const int wrow = mq * 80 + mt * 16 + r16;
    Wp[mt] = wrow < 32 ? (fw + wrow * 256)
           : wrow < 64 ? (gw + (wrow - 32) * 256)
                       : (hw + (wrow - 64) * 256);
  }
  // staging: thread -> k-row kk, 4 n-cols at nc
  const int kk = t >> 4, nc = (t & 15) * 4;
  f32x4 acc[5][2] = {};
  // prologue: stage k-step 0
  {
    f32x4 xv = *(const f32x4*)&xb[(size_t)kk * 4096 + n0 + nc];
    Bs[0][nc + 0][kk] = (__bf16)xv[0]; Bs[0][nc + 1][kk] = (__bf16)xv[1];
    Bs[0][nc + 2][kk] = (__bf16)xv[2]; Bs[0][nc + 3][kk] = (__bf16)xv[3];
  }
  __syncthreads();
  for (int ks = 0; ks < 8; ++ks) {
    const int cur = ks & 1;
    f32x4 xn;
    if (ks < 7) xn = *(const f32x4*)&xb[(size_t)((ks + 1) * 32 + kk) * 4096 + n0 + nc];
    bf16x8 bf0 = *(const bf16x8*)&Bs[cur][nsub * 32 + r16][h * 8];
    bf16x8 bf1 = *(const bf16x8*)&Bs[cur][nsub * 32 + 16 + r16][h * 8];
    #pragma unroll
    for (int mt = 0; mt < 5; ++mt) {
      f32x4 wlo = *(const f32x4*)(Wp[mt] + ks * 32 + h * 8);
      f32x4 whi = *(const f32x4*)(Wp[mt] + ks * 32 + h * 8 + 4);
      bf16x8 af = cvt8(wlo, whi);
      acc[mt][0] = __builtin_amdgcn_mfma_f32_16x16x32_bf16(af, bf0, acc[mt][0], 0, 0, 0);
      acc[mt][1] = __builtin_amdgcn_mfma_f32_16x16x32_bf16(af, bf1, acc[mt][1], 0, 0, 0);
    }
    if (ks < 7) {   // write next buffer (disjoint from cur): 1 barrier/step suffices
      const int nxt = cur ^ 1;
      Bs[nxt][nc + 0][kk] = (__bf16)xn[0]; Bs[nxt][nc + 1][kk] = (__bf16)xn[1];
      Bs[nxt][nc + 2][kk] = (__bf16)xn[2]; Bs[nxt][nc + 3][kk] = (__bf16)xn[3];
    }
    __syncthreads();
  }
  #pragma unroll
  for (int mt = 0; mt < 5; ++mt) {
    #pragma unroll
    for (int nt = 0; nt < 2; ++nt) {
      const int nn = n0 + nsub * 32 + nt * 16 + r16;
      #pragma unroll
      for (int r = 0; r < 4; ++r) {
        const int row = mq * 80 + mt * 16 + h * 4 + r;  // C/D: row=(lane>>4)*4+reg
        const float bias = row < 32 ? fb[row] : (row < 64 ? gb[row - 32] : hb[row - 64]);
        const float val = acc[mt][nt][r] + bias;
        if (row < 64) fgT[((size_t)b * 4096 + nn) * 64 + row] = (__bf16)val;
        else          hv[((size_t)b * 256 + (row - 64)) * 4096 + nn] = (__bf16)val;
      }
    }
  }
}

// ---------------- pass1: L[i] = sum_m exp(f_i . g_m)  (partial over m-quarter) ----
__global__ __launch_bounds__(256) void k_pass1(const __bf16* __restrict__ fgT,
                                               float* __restrict__ Lp) {
  const int bid = blockIdx.x;
  const int b = (bid & 7) >> 1;
  const int sub = ((bid >> 3) << 1) | (bid & 1);   // 0..255
  const int ms = sub >> 6, ib = sub & 63;
  const int w = threadIdx.x >> 6, lane = threadIdx.x & 63, r16 = lane & 15, h = lane >> 4;
  const int ibase = ib * 64 + w * 16;
  const __bf16* fg = fgT + (size_t)b * (4096 * 64);
  const bf16x8 afrag = *(const bf16x8*)(fg + (size_t)(ibase + r16) * 64 + h * 8);
  const f32x4 zero = {};
  float ls0 = 0.f, ls1 = 0.f, ls2 = 0.f, ls3 = 0.f;
  for (int mt = 0; mt < 64; mt += 2) {
    const int mb = ms * 1024 + mt * 16;
    bf16x8 g0 = *(const bf16x8*)(fg + (size_t)(mb + r16) * 64 + 32 + h * 8);
    bf16x8 g1 = *(const bf16x8*)(fg + (size_t)(mb + 16 + r16) * 64 + 32 + h * 8);
    f32x4 d0 = __builtin_amdgcn_mfma_f32_16x16x32_bf16(afrag, g0, zero, 0, 0, 0);
    f32x4 d1 = __builtin_amdgcn_mfma_f32_16x16x32_bf16(afrag, g1, zero, 0, 0, 0);
    ls0 += __expf(d0[0]) + __expf(d1[0]); ls1 += __expf(d0[1]) + __expf(d1[1]);
    ls2 += __expf(d0[2]) + __expf(d1[2]); ls3 += __expf(d0[3]) + __expf(d1[3]);
  }
  #pragma unroll
  for (int off = 1; off < 16; off <<= 1) {
    ls0 += __shfl_xor(ls0, off); ls1 += __shfl_xor(ls1, off);
    ls2 += __shfl_xor(ls2, off); ls3 += __shfl_xor(ls3, off);
  }
  if (r16 == 0) {
    f32x4 o = {ls0, ls1, ls2, ls3};
    *(f32x4*)&Lp[(size_t)(b * 4 + ms) * 4096 + ibase + h * 4] = o;
  }
}

// ---------------- wdiv: w = bf16(hv / L), in place, XCD-pinned ----------------
__global__ __launch_bounds__(256) void k_wdiv(__bf16* __restrict__ hv,
                                              const float* __restrict__ Lp) {
  const int bid = blockIdx.x;
  const int b = (bid & 7) >> 1;
  const int chunk = ((bid >> 3) << 1) | (bid & 1);  // 0..63
  const int base = b * 1048576 + chunk * 16384;     // base % 4096 == 0
  for (int i = threadIdx.x * 4; i < 16384; i += 1024) {
    const int e = base + i;
    const int j = i & 4095;
    bf16x4 h4 = *(const bf16x4*)(hv + e);
    const float* lp = Lp + (size_t)b * (4 * 4096) + j;
    f32x4 L = *(const f32x4*)lp;
    L += *(const f32x4*)(lp + 4096);
    L += *(const f32x4*)(lp + 8192);
    L += *(const f32x4*)(lp + 12288);
    bf16x4 o;
    o[0] = (__bf16)((float)h4[0] / L[0]); o[1] = (__bf16)((float)h4[1] / L[1]);
    o[2] = (__bf16)((float)h4[2] / L[2]); o[3] = (__bf16)((float)h4[3] / L[3]);
    *(bf16x4*)(hv + e) = o;
  }
}

// ---------------- pass2: sa[c,m] = sum_j w[c,j] exp(s[j,m]); out = gamma*sa + x ----
// 8 waves = (chalf, msub in {0,1}, jh in {0,1}): wave covers 128c x 32m x 32j.
// Cuts LDS w-reads to one-per-element-per-(c,j)-half: 64KB/iter (was 131KB).
// LDS [2][256][72] bf16 (stride-72: 16 distinct bank phases, reads/writes at floor).
// jh partial sums reduced once at end via LDS dump (wS dead by then).
// MFMA1 D (rows j, cols m) after exp is IN-REGISTER the B-fragment of MFMA2
// under the kappa map k = (lane>>4)*4 + (e&3) + 16*(e>>2).
__global__ __launch_bounds__(512, 1) void k_pass2(const __bf16* __restrict__ fgT,
    const __bf16* __restrict__ wbf, const float* __restrict__ x,
    const float* __restrict__ gamma, float* __restrict__ out) {
  __shared__ __bf16 wS[2][256][72];   // 73,728 B
  const int bid = blockIdx.x;
  const int b = (bid & 7) >> 1;                     // XCD pair per batch
  const int mblk = ((bid >> 3) << 1) | (bid & 1);   // 0..63
  const int t = threadIdx.x, w = t >> 6, lane = t & 63, r16 = lane & 15, h = lane >> 4;
  const int jh = w & 1, msub = (w >> 1) & 1, chalf = w >> 2;
  const int mbase = mblk * 64 + msub * 32;
  const __bf16* fg = fgT + (size_t)b * (4096 * 64);
  const __bf16* wb = wbf + (size_t)b * 256 * 4096;
  // gfrags: MFMA1 B operands (contiguous channel map), invariant over j
  const bf16x8 gf0 = *(const bf16x8*)(fg + (size_t)(mbase + r16) * 64 + 32 + h * 8);
  const bf16x8 gf1 = *(const bf16x8*)(fg + (size_t)(mbase + 16 + r16) * 64 + 32 + h * 8);
  // staging: thread t covers row t>>1, 32 j-elems at (t&1)*32, as 4x16B
  const int srow = t >> 1, scol = (t & 1) * 32;
  const __bf16* sgsrc = wb + (size_t)srow * 4096 + scol;
  __bf16* sd0 = &wS[0][srow][scol];
  __bf16* sd1 = &wS[1][srow][scol];

  f32x4 acc[8][2] = {};
  const f32x4 zero = {};

  // prologue: stage tile 0, load f fragments (own jh half) for tile 0
  #pragma unroll
  for (int c = 0; c < 4; ++c)
    *(uint4*)((char*)sd0 + c * 16) = *(const uint4*)(sgsrc + c * 8);
  bf16x8 fq0 = *(const bf16x8*)(fg + (size_t)(jh * 32 + r16) * 64 + h * 8);
  bf16x8 fq1 = *(const bf16x8*)(fg + (size_t)(jh * 32 + 16 + r16) * 64 + h * 8);
  __syncthreads();

  for (int it = 0; it < 64; ++it) {
    const int cur = it & 1;
    const int jbn = (it + 1) * 64;
    uint4 pw0, pw1, pw2, pw3; bf16x8 nf0, nf1;
    if (it < 63) {   // issue next-tile global loads early (L2-hot, hide under compute)
      pw0 = *(const uint4*)(sgsrc + jbn);
      pw1 = *(const uint4*)(sgsrc + jbn + 8);
      pw2 = *(const uint4*)(sgsrc + jbn + 16);
      pw3 = *(const uint4*)(sgsrc + jbn + 24);
      nf0 = *(const bf16x8*)(fg + (size_t)(jbn + jh * 32 + r16) * 64 + h * 8);
      nf1 = *(const bf16x8*)(fg + (size_t)(jbn + jh * 32 + 16 + r16) * 64 + h * 8);
    }
    // MFMA1 x4 + exp -> ef0 (mt0), ef1 (mt1); kappa layout on j within own half
    f32x4 d0 = __builtin_amdgcn_mfma_f32_16x16x32_bf16(fq0, gf0, zero, 0, 0, 0);
    f32x4 d1 = __builtin_amdgcn_mfma_f32_16x16x32_bf16(fq1, gf0, zero, 0, 0, 0);
    f32x4 d2 = __builtin_amdgcn_mfma_f32_16x16x32_bf16(fq0, gf1, zero, 0, 0, 0);
    f32x4 d3 = __builtin_amdgcn_mfma_f32_16x16x32_bf16(fq1, gf1, zero, 0, 0, 0);
    bf16x8 ef0, ef1;
    #pragma unroll
    for (int r = 0; r < 4; ++r) {
      ef0[r]     = (__bf16)__expf(d0[r]);
      ef0[4 + r] = (__bf16)__expf(d1[r]);
      ef1[r]     = (__bf16)__expf(d2[r]);
      ef1[4 + r] = (__bf16)__expf(d3[r]);
    }
    // MFMA2: 8 c-tiles; one w-frag per ct feeds both m-accumulators
    #pragma unroll
    for (int ct = 0; ct < 8; ++ct) {
      const char* rp = (const char*)&wS[cur][chalf * 128 + ct * 16 + r16][jh * 32];
      bf16x8 a = frag_cat(*(const bf16x4*)(rp + h * 8),
                          *(const bf16x4*)(rp + h * 8 + 32));
      acc[ct][0] = __builtin_amdgcn_mfma_f32_16x16x32_bf16(a, ef0, acc[ct][0], 0, 0, 0);
      acc[ct][1] = __builtin_amdgcn_mfma_f32_16x16x32_bf16(a, ef1, acc[ct][1], 0, 0, 0);
    }
    if (it < 63) {   // write next tile into the other buffer
      __bf16* sd = cur ? sd0 : sd1;
      *(uint4*)((char*)sd +  0) = pw0;
      *(uint4*)((char*)sd + 16) = pw1;
      *(uint4*)((char*)sd + 32) = pw2;
      *(uint4*)((char*)sd + 48) = pw3;
      fq0 = nf0; fq1 = nf1;
    }
    __syncthreads();
  }

  // jh reduction: jh=1 waves dump 16 f32x4 each into wS (dead), jh=0 adds.
  float* red = (float*)wS;
  const int region = (chalf * 2 + msub) * 4096;     // 4 regions x 16KB (floats)
  if (jh == 1) {
    #pragma unroll
    for (int ct = 0; ct < 8; ++ct)
      #pragma unroll
      for (int mt = 0; mt < 2; ++mt)
        *(f32x4*)&red[region + ((ct * 2 + mt) * 64 + lane) * 4] = acc[ct][mt];
  }
  __syncthreads();
  if (jh == 0) {
    const float gm = gamma[0];
    const float* xb = x + (size_t)b * (256 * 4096);
    float* ob = out + (size_t)b * (256 * 4096);
    #pragma unroll
    for (int ct = 0; ct < 8; ++ct) {
      #pragma unroll
      for (int mt = 0; mt < 2; ++mt) {
        f32x4 o = *(const f32x4*)&red[region + ((ct * 2 + mt) * 64 + lane) * 4];
        o += acc[ct][mt];
        #pragma unroll
        for (int r = 0; r < 4; ++r) {
          const int c = chalf * 128 + ct * 16 + h * 4 + r;
          const size_t idx = (size_t)c * 4096 + (mbase + mt * 16 + r16);
          ob[idx] = gm * o[r] + xb[idx];
        }
      }
    }
  }
}

extern "C" void kernel_launch(void* const* d_in, const int* in_sizes, int n_in,
                              void* d_out, int out_size, void* d_ws, size_t ws_size,
                              hipStream_t stream) {
  const float* x     = (const float*)d_in[0];
  const float* fw    = (const float*)d_in[1];
  const float* fb    = (const float*)d_in[2];
  const float* gw    = (const float*)d_in[3];
  const float* gb    = (const float*)d_in[4];
  const float* hw    = (const float*)d_in[5];
  const float* hb    = (const float*)d_in[6];
  const float* gamma = (const float*)d_in[7];
  float* out = (float*)d_out;

  char* wsb = (char*)d_ws;
  __bf16* fgT = (__bf16*)(wsb);
  __bf16* hv  = (__bf16*)(wsb + 2097152);
  float*  Lp  = (float*) (wsb + 10485760);

  k_proj<<<dim3(256), dim3(512), 0, stream>>>(fw, gw, hw, x, fb, gb, hb, fgT, hv);
  k_pass1<<<dim3(1024), dim3(256), 0, stream>>>(fgT, Lp);
  k_wdiv<<<dim3(256), dim3(256), 0, stream>>>(hv, Lp);
  k_pass2<<<dim3(256), dim3(512), 0, stream>>>(fgT, hv, x, gamma, out);
}